// Round 2
// baseline (2073.287 us; speedup 1.0000x reference)
//
#include <hip/hip_runtime.h>
#include <stdint.h>

// QuantizedLinear: y = x @ quantdequant(w).T + bias   (M=8192, N=4096, K=4096)
//
// w -> q (int4 values stored as EXACT bf16) + scale[g][n] (fp32)   [quant_pre]
// x -> xh + xl bf16 planes (x to ~2^-17 rel)                        [xsplit]
// GEMM: pacc = sum_{k in 128-group} q*(xh+xl) via 2 bf16 MFMAs per 32-chunk,
//       acc += scale * pacc per group. ~1e-5 rel error at bf16-MFMA speed.
// GEMM structure: m97-style 128x128/BK=64, all planes via global_load_lds(16B)
// with pre-swizzled global source + XOR-swizzled ds_read (0 conflicts, R1-proven),
// 48KB LDS single-buffered -> 3 blocks/CU, 2-barrier K-loop.

#define BM 128
#define BN 128
#define BK 64
#define GS 128

typedef float    f32x4 __attribute__((ext_vector_type(4)));
typedef uint32_t u32x4 __attribute__((ext_vector_type(4)));
typedef uint32_t u32x2 __attribute__((ext_vector_type(2)));

__device__ __forceinline__ uint16_t f2bf(float f) {
  uint32_t u = __float_as_uint(f);
  uint32_t r = u + 0x7FFFu + ((u >> 16) & 1u);   // RNE, finite inputs
  return (uint16_t)(r >> 16);
}
__device__ __forceinline__ float bf2f(uint16_t h) {
  return __uint_as_float((uint32_t)h << 16);
}
__device__ __forceinline__ void gload_lds16(const void* g, void* l) {
  __builtin_amdgcn_global_load_lds(
      (const __attribute__((address_space(1))) void*)g,
      (__attribute__((address_space(3))) void*)l, 16, 0, 0);
}
__device__ __forceinline__ void mfma16x16x32bf16(f32x4& d, const u32x4& a, const u32x4& b) {
  asm("v_mfma_f32_16x16x32_bf16 %0, %1, %2, %0" : "+v"(d) : "v"(a), "v"(b));
}

// ---------------- pre-pass 1: group-wise int4 fake-quant of w ----------------
// thread = 4 elems (float4); 32-lane half-wave = one 128-group.
__global__ void quant_pre(const float* __restrict__ w, uint16_t* __restrict__ q,
                          float* __restrict__ scales, int N, int K) {
  size_t t = (size_t)blockIdx.x * blockDim.x + threadIdx.x;
  size_t base = t * 4;
  if (base >= (size_t)N * K) return;
  int lane = threadIdx.x & 63;
  float4 v = *reinterpret_cast<const float4*>(w + base);
  float a = fmaxf(fmaxf(fabsf(v.x), fabsf(v.y)), fmaxf(fabsf(v.z), fabsf(v.w)));
#pragma unroll
  for (int off = 16; off > 0; off >>= 1) a = fmaxf(a, __shfl_xor(a, off));
  float scale = a / 7.0f;                       // absmax/QMAX, matches ref
  float ss = (scale > 0.0f) ? scale : 1.0f;
  float q0 = fminf(fmaxf(rintf(v.x / ss), -8.0f), 7.0f);   // rintf = RNE = jnp.round
  float q1 = fminf(fmaxf(rintf(v.y / ss), -8.0f), 7.0f);
  float q2 = fminf(fmaxf(rintf(v.z / ss), -8.0f), 7.0f);
  float q3 = fminf(fmaxf(rintf(v.w / ss), -8.0f), 7.0f);
  u32x2 pk = { (uint32_t)f2bf(q0) | ((uint32_t)f2bf(q1) << 16),
               (uint32_t)f2bf(q2) | ((uint32_t)f2bf(q3) << 16) };
  *reinterpret_cast<u32x2*>(q + base) = pk;
  if ((lane & 31) == 0) {
    size_t fg = base >> 7;                      // flat group id = n*(K/128)+g
    int gpr = K >> 7;
    scales[(fg % gpr) * (size_t)N + (fg / gpr)] = scale;
  }
}

// ---------------- pre-pass 2: x -> xh,xl bf16 planes -------------------------
__global__ void xsplit(const float* __restrict__ x, uint16_t* __restrict__ xh,
                       uint16_t* __restrict__ xl, size_t n8) {
  size_t t = (size_t)blockIdx.x * blockDim.x + threadIdx.x;
  if (t >= n8) return;
  const float4* p = reinterpret_cast<const float4*>(x) + t * 2;
  float4 a = p[0], b = p[1];
  float f[8] = {a.x, a.y, a.z, a.w, b.x, b.y, b.z, b.w};
  uint16_t h[8], l[8];
#pragma unroll
  for (int e = 0; e < 8; ++e) {
    h[e] = f2bf(f[e]);
    l[e] = f2bf(f[e] - bf2f(h[e]));
  }
  u32x4 hv = { (uint32_t)h[0] | ((uint32_t)h[1] << 16),
               (uint32_t)h[2] | ((uint32_t)h[3] << 16),
               (uint32_t)h[4] | ((uint32_t)h[5] << 16),
               (uint32_t)h[6] | ((uint32_t)h[7] << 16) };
  u32x4 lv = { (uint32_t)l[0] | ((uint32_t)l[1] << 16),
               (uint32_t)l[2] | ((uint32_t)l[3] << 16),
               (uint32_t)l[4] | ((uint32_t)l[5] << 16),
               (uint32_t)l[6] | ((uint32_t)l[7] << 16) };
  *reinterpret_cast<u32x4*>(xh + t * 8) = hv;
  *reinterpret_cast<u32x4*>(xl + t * 8) = lv;
}

// ------------------------------- GEMM (new) ----------------------------------
__global__ __launch_bounds__(256, 3) void qgemm(
    const uint16_t* __restrict__ xh, const uint16_t* __restrict__ xl,
    const uint16_t* __restrict__ q, const float* __restrict__ scales,
    const float* __restrict__ bias, float* __restrict__ out,
    int M, int N, int K) {
  __shared__ uint16_t sAh[BM * BK];   // 16 KB
  __shared__ uint16_t sAl[BM * BK];   // 16 KB
  __shared__ uint16_t sB[BN * BK];    // 16 KB  -> 48 KB total, 3 blocks/CU

  const int tid = threadIdx.x;
  const int lane = tid & 63;
  const int wid = tid >> 6;
  const int wm = wid >> 1;
  const int wn = wid & 1;

  int nblkTotal = N / BN;
  int bid = (int)blockIdx.x;
  int nwg = (int)gridDim.x;
  int id = bid;
  if ((nwg & 7) == 0) { int cpx = nwg >> 3; id = (bid & 7) * cpx + (bid >> 3); }
  const int mbase = (id / nblkTotal) * BM;
  const int nbase = (id % nblkTotal) * BN;
  const int nt = K / BK;

  const uint16_t* xhp = xh + (size_t)mbase * K;
  const uint16_t* xlp = xl + (size_t)mbase * K;
  const uint16_t* qp  = q  + (size_t)nbase * K;

  f32x4 acc[4][4] = {};
  f32x4 pacc[4][4] = {};
  float sreg[4];

  auto issuePlane = [&](const uint16_t* src0, uint16_t* lds, int t) {
#pragma unroll
    for (int i = 0; i < 4; ++i) {
      int gran = i * 256 + tid;                 // 16B granule index
      int row = gran >> 3;
      int slot = gran & 7;
      const uint16_t* src = src0 + (size_t)row * K + (size_t)t * BK
                                 + ((slot ^ (row & 7)) << 3);
      gload_lds16(src, &lds[(size_t)(i * 256 + wid * 64) * 8]); // wave-uniform base
    }
  };

  auto computeTile = [&]() {
#pragma unroll
    for (int kk = 0; kk < 2; ++kk) {
      u32x4 ah[4], al[4], bf[4];
#pragma unroll
      for (int i = 0; i < 4; ++i) {
        int row = wm * 64 + i * 16 + (lane & 15);
        int slot = kk * 4 + (lane >> 4);
        int boff = row * 128 + ((slot ^ (row & 7)) << 4);
        ah[i] = *reinterpret_cast<const u32x4*>(reinterpret_cast<const char*>(sAh) + boff);
        al[i] = *reinterpret_cast<const u32x4*>(reinterpret_cast<const char*>(sAl) + boff);
      }
#pragma unroll
      for (int j = 0; j < 4; ++j) {
        int row = wn * 64 + j * 16 + (lane & 15);
        int slot = kk * 4 + (lane >> 4);
        int boff = row * 128 + ((slot ^ (row & 7)) << 4);
        bf[j] = *reinterpret_cast<const u32x4*>(reinterpret_cast<const char*>(sB) + boff);
      }
#pragma unroll
      for (int i = 0; i < 4; ++i)
#pragma unroll
        for (int j = 0; j < 4; ++j) {
          mfma16x16x32bf16(pacc[i][j], ah[i], bf[j]);
          mfma16x16x32bf16(pacc[i][j], al[i], bf[j]);
        }
    }
  };

  issuePlane(xhp, sAh, 0);
  issuePlane(xlp, sAl, 0);
  issuePlane(qp,  sB,  0);
  __syncthreads();                       // implicit vmcnt(0) drain

  for (int t = 0; t < nt; ++t) {
    if ((t & 1) == 0) {
      int g = t >> 1;
#pragma unroll
      for (int j = 0; j < 4; ++j)
        sreg[j] = scales[(size_t)g * N + nbase + wn * 64 + j * 16 + (lane & 15)];
    }
    computeTile();
    if (t & 1) {                          // end of 128-group: fold scale
#pragma unroll
      for (int j = 0; j < 4; ++j) {
        float s = sreg[j];
#pragma unroll
        for (int i = 0; i < 4; ++i) {
#pragma unroll
          for (int r = 0; r < 4; ++r) acc[i][j][r] += s * pacc[i][j][r];
          pacc[i][j] = (f32x4){0.f, 0.f, 0.f, 0.f};
        }
      }
    }
    __syncthreads();                      // all waves done reading LDS(t)
    if (t + 1 < nt) {
      issuePlane(xhp, sAh, t + 1);
      issuePlane(xlp, sAl, t + 1);
      issuePlane(qp,  sB,  t + 1);
    }
    __syncthreads();                      // vmcnt drained -> LDS(t+1) ready
  }

  // epilogue: C/D layout col = lane&15, row = (lane>>4)*4 + r  (R1-verified)
#pragma unroll
  for (int j = 0; j < 4; ++j) {
    int n = nbase + wn * 64 + j * 16 + (lane & 15);
    float b = bias[n];
#pragma unroll
    for (int i = 0; i < 4; ++i) {
      int m0 = mbase + wm * 64 + i * 16 + ((lane >> 4) << 2);
#pragma unroll
      for (int r = 0; r < 4; ++r)
        out[(size_t)(m0 + r) * N + n] = acc[i][j][r] + b;
    }
  }
}

// ---------------- fallback GEMM (round-1, needs only q+scales) ---------------
__global__ __launch_bounds__(256, 2) void qgemm_v1(
    const float* __restrict__ x, const uint16_t* __restrict__ q,
    const float* __restrict__ scales, const float* __restrict__ bias,
    float* __restrict__ out, int M, int N, int K) {
  __shared__ uint16_t sAh[BM * BK];
  __shared__ uint16_t sAl[BM * BK];
  __shared__ uint16_t sB[2][BN * BK];

  const int tid = threadIdx.x;
  const int lane = tid & 63;
  const int wid = tid >> 6;
  const int wm = wid >> 1;
  const int wn = wid & 1;

  int nblkTotal = N / BN;
  int bid = (int)blockIdx.x;
  int nwg = (int)gridDim.x;
  int id = bid;
  if ((nwg & 7) == 0) { int cpx = nwg >> 3; id = (bid & 7) * cpx + (bid >> 3); }
  const int mbase = (id / nblkTotal) * BM;
  const int nbase = (id % nblkTotal) * BN;
  const int nt = K / BK;

  f32x4 acc[4][4] = {};
  f32x4 pacc[4][4] = {};
  float sreg[4];
  float4 areg[8];

  auto loadA = [&](int t) {
#pragma unroll
    for (int p = 0; p < 8; ++p) {
      int idx = p * 256 + tid;
      int row = idx >> 4;
      int f4 = idx & 15;
      areg[p] = *reinterpret_cast<const float4*>(
          x + (size_t)(mbase + row) * K + (size_t)t * BK + f4 * 4);
    }
  };
  auto writeA = [&]() {
#pragma unroll
    for (int p = 0; p < 8; ++p) {
      int idx = p * 256 + tid;
      int row = idx >> 4;
      int f4 = idx & 15;
      int boff = row * 128 + (((f4 >> 1) ^ (row & 7)) << 4) + ((f4 & 1) << 3);
      float fx[4] = {areg[p].x, areg[p].y, areg[p].z, areg[p].w};
      uint16_t h[4], l[4];
#pragma unroll
      for (int e = 0; e < 4; ++e) {
        h[e] = f2bf(fx[e]);
        l[e] = f2bf(fx[e] - bf2f(h[e]));
      }
      u32x2 hv = { (uint32_t)h[0] | ((uint32_t)h[1] << 16),
                   (uint32_t)h[2] | ((uint32_t)h[3] << 16) };
      u32x2 lv = { (uint32_t)l[0] | ((uint32_t)l[1] << 16),
                   (uint32_t)l[2] | ((uint32_t)l[3] << 16) };
      *reinterpret_cast<u32x2*>(reinterpret_cast<char*>(sAh) + boff) = hv;
      *reinterpret_cast<u32x2*>(reinterpret_cast<char*>(sAl) + boff) = lv;
    }
  };
  auto issueB = [&](int t, int buf) {
#pragma unroll
    for (int i = 0; i < 4; ++i) {
      int gran = i * 256 + wid * 64 + lane;
      int row = gran >> 3;
      int slot = gran & 7;
      const uint16_t* src = q + (size_t)(nbase + row) * K + (size_t)t * BK
                              + ((slot ^ (row & 7)) << 3);
      gload_lds16(src, &sB[buf][(size_t)(i * 256 + wid * 64) * 8]);
    }
  };
  auto computeTile = [&](int buf) {
#pragma unroll
    for (int kk = 0; kk < 2; ++kk) {
      u32x4 ah[4], al[4], bf[4];
#pragma unroll
      for (int i = 0; i < 4; ++i) {
        int row = wm * 64 + i * 16 + (lane & 15);
        int slot = kk * 4 + (lane >> 4);
        int boff = row * 128 + ((slot ^ (row & 7)) << 4);
        ah[i] = *reinterpret_cast<const u32x4*>(reinterpret_cast<const char*>(sAh) + boff);
        al[i] = *reinterpret_cast<const u32x4*>(reinterpret_cast<const char*>(sAl) + boff);
      }
#pragma unroll
      for (int j = 0; j < 4; ++j) {
        int row = wn * 64 + j * 16 + (lane & 15);
        int slot = kk * 4 + (lane >> 4);
        int boff = row * 128 + ((slot ^ (row & 7)) << 4);
        bf[j] = *reinterpret_cast<const u32x4*>(reinterpret_cast<const char*>(sB[buf]) + boff);
      }
#pragma unroll
      for (int i = 0; i < 4; ++i)
#pragma unroll
        for (int j = 0; j < 4; ++j) {
          mfma16x16x32bf16(pacc[i][j], ah[i], bf[j]);
          mfma16x16x32bf16(pacc[i][j], al[i], bf[j]);
        }
    }
  };

  loadA(0);
  issueB(0, 0);
  writeA();
  __syncthreads();

  int cur = 0;
  for (int t = 0; t < nt; ++t) {
    if (t + 1 < nt) {
      issueB(t + 1, cur ^ 1);
      loadA(t + 1);
    }
    if ((t & 1) == 0) {
      int g = t >> 1;
#pragma unroll
      for (int j = 0; j < 4; ++j)
        sreg[j] = scales[(size_t)g * N + nbase + wn * 64 + j * 16 + (lane & 15)];
    }
    computeTile(cur);
    if (t & 1) {
#pragma unroll
      for (int j = 0; j < 4; ++j) {
        float s = sreg[j];
#pragma unroll
        for (int i = 0; i < 4; ++i) {
#pragma unroll
          for (int r = 0; r < 4; ++r) acc[i][j][r] += s * pacc[i][j][r];
          pacc[i][j] = (f32x4){0.f, 0.f, 0.f, 0.f};
        }
      }
    }
    __syncthreads();
    if (t + 1 < nt) writeA();
    __syncthreads();
    cur ^= 1;
  }

#pragma unroll
  for (int j = 0; j < 4; ++j) {
    int n = nbase + wn * 64 + j * 16 + (lane & 15);
    float b = bias[n];
#pragma unroll
    for (int i = 0; i < 4; ++i) {
      int m0 = mbase + wm * 64 + i * 16 + ((lane >> 4) << 2);
#pragma unroll
      for (int r = 0; r < 4; ++r)
        out[(size_t)(m0 + r) * N + n] = acc[i][j][r] + b;
    }
  }
}

extern "C" void kernel_launch(void* const* d_in, const int* in_sizes, int n_in,
                              void* d_out, int out_size, void* d_ws, size_t ws_size,
                              hipStream_t stream) {
  const float* x = (const float*)d_in[0];
  const float* w = (const float*)d_in[1];
  const float* bias = (const float*)d_in[2];
  float* out = (float*)d_out;

  int N = in_sizes[2];                   // 4096
  int K = in_sizes[1] / N;               // 4096
  int M = in_sizes[0] / K;               // 8192

  size_t qB  = (size_t)N * K * sizeof(uint16_t);
  size_t scB = (size_t)(K / GS) * N * sizeof(float);
  size_t xB  = (size_t)M * K * sizeof(uint16_t);

  uint16_t* q = (uint16_t*)d_ws;
  float* scales = (float*)((char*)d_ws + qB);

  int preBlocks = (int)(((size_t)N * K / 4 + 255) / 256);
  quant_pre<<<preBlocks, 256, 0, stream>>>(w, q, scales, N, K);

  dim3 grid((M / BM) * (N / BN));

  if (ws_size >= qB + scB + 2 * xB) {
    uint16_t* xh = (uint16_t*)((char*)d_ws + qB + scB);
    uint16_t* xl = (uint16_t*)((char*)d_ws + qB + scB + xB);
    size_t n8 = (size_t)M * K / 8;
    int xsBlocks = (int)((n8 + 255) / 256);
    xsplit<<<xsBlocks, 256, 0, stream>>>(x, xh, xl, n8);
    qgemm<<<grid, 256, 0, stream>>>(xh, xl, q, scales, bias, out, M, N, K);
  } else {
    qgemm_v1<<<grid, 256, 0, stream>>>(x, q, scales, bias, out, M, N, K);
  }
}

// Round 4
// 566.698 us; speedup vs baseline: 3.6585x; 3.6585x over previous
//
#include <hip/hip_runtime.h>
#include <stdint.h>

// QuantizedLinear: y = x @ quantdequant(w).T + bias   (M=8192, N=4096, K=4096)
//
// R4 scheme: fold scale at pre-pass -> wq = bf16(clip(round(w/s))*s)  [quant_pre]
//            x -> bf16                                                 [xcast]
//            plain bf16 GEMM (fp32 acc) + bias.
// Error budget: x-side + w-side bf16 rounding ~0.008 absmax each on top of
// measured 0.031 quant tie-noise => ~0.045 << 0.146 threshold.
//
// Structure discipline (R3 raced under graph replay): ONLY replay-proven
// patterns — sB[2] dbuf with prefetch issued at top of compute (R1-proven),
// sA single-buffered, issued strictly between the two barriers (R2-proven).
// 48KB LDS, __launch_bounds__(256,2) (R2 lesson: (256,3) spilled accumulators).

#define BM 128
#define BN 128
#define BK 64

typedef float    f32x4 __attribute__((ext_vector_type(4)));
typedef uint32_t u32x4 __attribute__((ext_vector_type(4)));
typedef uint32_t u32x2 __attribute__((ext_vector_type(2)));

__device__ __forceinline__ uint16_t f2bf(float f) {
  uint32_t u = __float_as_uint(f);
  uint32_t r = u + 0x7FFFu + ((u >> 16) & 1u);   // RNE, finite inputs
  return (uint16_t)(r >> 16);
}
__device__ __forceinline__ void gload_lds16(const void* g, void* l) {
  __builtin_amdgcn_global_load_lds(
      (const __attribute__((address_space(1))) void*)g,
      (__attribute__((address_space(3))) void*)l, 16, 0, 0);
}
__device__ __forceinline__ void mfma16x16x32bf16(f32x4& d, const u32x4& a, const u32x4& b) {
  asm("v_mfma_f32_16x16x32_bf16 %0, %1, %2, %0" : "+v"(d) : "v"(a), "v"(b));
}

// ------ pre-pass 1: group-wise int4 fake-quant of w, scale folded, bf16 out --
// thread = 4 elems (float4); 32-lane half-wave = one 128-group.
__global__ void quant_pre(const float* __restrict__ w, uint16_t* __restrict__ wq,
                          size_t total) {
  size_t t = (size_t)blockIdx.x * blockDim.x + threadIdx.x;
  size_t base = t * 4;
  if (base >= total) return;
  float4 v = *reinterpret_cast<const float4*>(w + base);
  float a = fmaxf(fmaxf(fabsf(v.x), fabsf(v.y)), fmaxf(fabsf(v.z), fabsf(v.w)));
#pragma unroll
  for (int off = 16; off > 0; off >>= 1) a = fmaxf(a, __shfl_xor(a, off));
  float scale = a / 7.0f;                       // absmax/QMAX, matches ref
  float ss = (scale > 0.0f) ? scale : 1.0f;
  float q0 = fminf(fmaxf(rintf(v.x / ss), -8.0f), 7.0f);   // rintf = RNE = jnp.round
  float q1 = fminf(fmaxf(rintf(v.y / ss), -8.0f), 7.0f);
  float q2 = fminf(fmaxf(rintf(v.z / ss), -8.0f), 7.0f);
  float q3 = fminf(fmaxf(rintf(v.w / ss), -8.0f), 7.0f);
  u32x2 pk = { (uint32_t)f2bf(q0 * scale) | ((uint32_t)f2bf(q1 * scale) << 16),
               (uint32_t)f2bf(q2 * scale) | ((uint32_t)f2bf(q3 * scale) << 16) };
  *reinterpret_cast<u32x2*>(wq + base) = pk;
}

// ------ pre-pass 2: x -> bf16 ------------------------------------------------
__global__ void xcast(const float* __restrict__ x, uint16_t* __restrict__ xb,
                      size_t n8) {
  size_t t = (size_t)blockIdx.x * blockDim.x + threadIdx.x;
  if (t >= n8) return;
  const float4* p = reinterpret_cast<const float4*>(x) + t * 2;
  float4 a = p[0], b = p[1];
  float f[8] = {a.x, a.y, a.z, a.w, b.x, b.y, b.z, b.w};
  u32x4 hv = { (uint32_t)f2bf(f[0]) | ((uint32_t)f2bf(f[1]) << 16),
               (uint32_t)f2bf(f[2]) | ((uint32_t)f2bf(f[3]) << 16),
               (uint32_t)f2bf(f[4]) | ((uint32_t)f2bf(f[5]) << 16),
               (uint32_t)f2bf(f[6]) | ((uint32_t)f2bf(f[7]) << 16) };
  *reinterpret_cast<u32x4*>(xb + t * 8) = hv;
}

// ------------------------------- GEMM ----------------------------------------
// 128x128, BK=64, 4 waves (2x2), each wave 64x64 via 4x4 frags of 16x16x32.
// LDS 48KB: sB[2] dbuf (prefetch at top of compute, R1-proven),
//           sA single (issued between barriers, R2-proven). 2 blocks/CU.
__global__ __launch_bounds__(256, 2) void qgemm(
    const uint16_t* __restrict__ xb, const uint16_t* __restrict__ wq,
    const float* __restrict__ bias, float* __restrict__ out,
    int M, int N, int K) {
  __shared__ uint16_t sA[BM * BK];       // 16 KB
  __shared__ uint16_t sB[2][BN * BK];    // 32 KB

  const int tid = threadIdx.x;
  const int lane = tid & 63;
  const int wid = tid >> 6;
  const int wm = wid >> 1;
  const int wn = wid & 1;

  int nblkTotal = N / BN;
  int bid = (int)blockIdx.x;
  int nwg = (int)gridDim.x;
  int id = bid;
  if ((nwg & 7) == 0) { int cpx = nwg >> 3; id = (bid & 7) * cpx + (bid >> 3); }
  const int mbase = (id / nblkTotal) * BM;
  const int nbase = (id % nblkTotal) * BN;
  const int nt = K / BK;

  const uint16_t* ap = xb + (size_t)mbase * K;
  const uint16_t* bp = wq + (size_t)nbase * K;

  f32x4 acc[4][4] = {};

  auto issuePlane = [&](const uint16_t* src0, uint16_t* lds, int t) {
#pragma unroll
    for (int i = 0; i < 4; ++i) {
      int gran = i * 256 + tid;                 // 16B granule index
      int row = gran >> 3;
      int slot = gran & 7;
      const uint16_t* src = src0 + (size_t)row * K + (size_t)t * BK
                                 + ((slot ^ (row & 7)) << 3);
      gload_lds16(src, &lds[(size_t)(i * 256 + wid * 64) * 8]); // wave-uniform base
    }
  };

  auto computeTile = [&](int buf) {
#pragma unroll
    for (int kk = 0; kk < 2; ++kk) {
      u32x4 av[4], bv[4];
#pragma unroll
      for (int i = 0; i < 4; ++i) {
        int row = wm * 64 + i * 16 + (lane & 15);
        int slot = kk * 4 + (lane >> 4);
        int boff = row * 128 + ((slot ^ (row & 7)) << 4);
        av[i] = *reinterpret_cast<const u32x4*>(reinterpret_cast<const char*>(sA) + boff);
      }
#pragma unroll
      for (int j = 0; j < 4; ++j) {
        int row = wn * 64 + j * 16 + (lane & 15);
        int slot = kk * 4 + (lane >> 4);
        int boff = row * 128 + ((slot ^ (row & 7)) << 4);
        bv[j] = *reinterpret_cast<const u32x4*>(reinterpret_cast<const char*>(sB[buf]) + boff);
      }
#pragma unroll
      for (int i = 0; i < 4; ++i)
#pragma unroll
        for (int j = 0; j < 4; ++j)
          mfma16x16x32bf16(acc[i][j], av[i], bv[j]);
    }
  };

  // prologue: stage tile 0
  issuePlane(bp, sB[0], 0);
  issuePlane(ap, sA,    0);
  __syncthreads();                       // implicit vmcnt(0) drain

  int cur = 0;
  for (int t = 0; t < nt; ++t) {
    if (t + 1 < nt) issuePlane(bp, sB[cur ^ 1], t + 1);  // prefetch, hides under MFMA
    computeTile(cur);
    __syncthreads();                     // all waves done reading sA(t)
    if (t + 1 < nt) issuePlane(ap, sA, t + 1);
    __syncthreads();                     // vmcnt drained -> tile t+1 ready
    cur ^= 1;
  }

  // epilogue: C/D layout col = lane&15, row = (lane>>4)*4 + r  (verified R1)
#pragma unroll
  for (int j = 0; j < 4; ++j) {
    int n = nbase + wn * 64 + j * 16 + (lane & 15);
    float b = bias[n];
#pragma unroll
    for (int i = 0; i < 4; ++i) {
      int m0 = mbase + wm * 64 + i * 16 + ((lane >> 4) << 2);
#pragma unroll
      for (int r = 0; r < 4; ++r)
        out[(size_t)(m0 + r) * N + n] = acc[i][j][r] + b;
    }
  }
}

extern "C" void kernel_launch(void* const* d_in, const int* in_sizes, int n_in,
                              void* d_out, int out_size, void* d_ws, size_t ws_size,
                              hipStream_t stream) {
  const float* x = (const float*)d_in[0];
  const float* w = (const float*)d_in[1];
  const float* bias = (const float*)d_in[2];
  float* out = (float*)d_out;

  int N = in_sizes[2];                   // 4096
  int K = in_sizes[1] / N;               // 4096
  int M = in_sizes[0] / K;               // 8192

  size_t wqB = (size_t)N * K * sizeof(uint16_t);   // 32 MiB
  uint16_t* wq = (uint16_t*)d_ws;
  uint16_t* xb = (uint16_t*)((char*)d_ws + wqB);   // 64 MiB

  size_t totalW = (size_t)N * K;
  int preBlocks = (int)((totalW / 4 + 255) / 256);
  quant_pre<<<preBlocks, 256, 0, stream>>>(w, wq, totalW);

  size_t n8 = (size_t)M * K / 8;
  int xcBlocks = (int)((n8 + 255) / 256);
  xcast<<<xcBlocks, 256, 0, stream>>>(x, xb, n8);

  dim3 grid((M / BM) * (N / BN));
  qgemm<<<grid, 256, 0, stream>>>(xb, wq, bias, out, M, N, K);
}